// Round 2
// baseline (354.529 us; speedup 1.0000x reference)
//
#include <hip/hip_runtime.h>
#include <stdint.h>

// Problem constants
#define NB 4
#define TT 2048
#define CC 1024
#define NH 16
#define DD 64
#define BHH (NB*NH)     // 64 (b,h) pairs
#define MROWS (NB*TT)   // 8192

typedef uint16_t u16;
typedef __bf16 bf16x8 __attribute__((ext_vector_type(8)));
typedef float f32x4 __attribute__((ext_vector_type(4)));

__device__ __forceinline__ u16 f2bf(float f) {
    union { float f; uint32_t u; } v; v.f = f;
    uint32_t u = v.u;
    return (u16)((u + 0x7FFF + ((u >> 16) & 1)) >> 16);   // RNE
}

__device__ __forceinline__ void gl_lds16(const u16* g, u16* l) {
    // async global->LDS, 16B per lane; LDS dest is wave-uniform base + lane*16
    __builtin_amdgcn_global_load_lds(
        (const __attribute__((address_space(1))) unsigned int*)g,
        (__attribute__((address_space(3))) unsigned int*)l, 16, 0, 0);
}

__device__ __forceinline__ f32x4 mfma16(bf16x8 a, bf16x8 b, f32x4 c) {
    return __builtin_amdgcn_mfma_f32_16x16x32_bf16(a, b, c, 0, 0, 0);
}

// ---------------------------------------------------------------------------
// f32 -> bf16 elementwise convert (vectorized), n % 1024 == 0
// ---------------------------------------------------------------------------
__global__ __launch_bounds__(256) void k_f2b(const float* __restrict__ in,
                                             u16* __restrict__ out, int n) {
    const int i = (blockIdx.x * 256 + threadIdx.x) * 4;
    if (i >= n) return;
    const float4 v = *(const float4*)(in + i);
    ushort4 o;
    o.x = f2bf(v.x); o.y = f2bf(v.y); o.z = f2bf(v.z); o.w = f2bf(v.w);
    *(ushort4*)(out + i) = o;
}

// ---------------------------------------------------------------------------
// Weight transpose + convert: in f32 [R][N] -> out bf16 [N][R]
// ---------------------------------------------------------------------------
__global__ __launch_bounds__(256) void k_transpose_cvt(const float* __restrict__ in,
                                                       u16* __restrict__ out,
                                                       int R, int N) {
    __shared__ float t[32][33];
    const int n0 = blockIdx.x * 32, r0 = blockIdx.y * 32;
    const int c  = threadIdx.x & 31, rq = threadIdx.x >> 5;   // rq 0..7
#pragma unroll
    for (int i = 0; i < 4; ++i) {
        int r = rq + i * 8;
        t[r][c] = in[(r0 + r) * N + n0 + c];
    }
    __syncthreads();
#pragma unroll
    for (int i = 0; i < 4; ++i) {
        int r = rq + i * 8;
        out[(n0 + r) * R + r0 + c] = f2bf(t[c][r]);
    }
}

// ---------------------------------------------------------------------------
// GEMM core (m97 structure): C_tile[128x128] = A[128xK] * Bt[128xK]^T
// A row-major bf16 [M][1024], Bt row-major bf16 [N][1024]. 256 threads,
// 4 waves 2x2, 64x64 per wave = 4x4 frags of 16x16, BK=32, 16x16x32 MFMA.
// ---------------------------------------------------------------------------
__device__ __forceinline__ void gemm_tile(const u16* __restrict__ A,
                                          const u16* __restrict__ Bt,
                                          int m0, int n0, f32x4 acc[4][4]) {
    __shared__ __align__(16) u16 As[128 * 32];
    __shared__ __align__(16) u16 Bs[128 * 32];
    const int tid = threadIdx.x;
    const int l = tid & 63, w = tid >> 6;
    const int wr = w >> 1, wc = w & 1;
    const int lr = l & 15, lg = l >> 4;
    const int srow = tid >> 2;            // 0..63
    const int scolh = (tid & 3) << 3;     // ushort col 0,8,16,24

    const u16* a0 = A + (m0 + srow) * 1024 + scolh;
    const u16* a1 = A + (m0 + 64 + srow) * 1024 + scolh;
    const u16* b0 = Bt + (n0 + srow) * 1024 + scolh;
    const u16* b1 = Bt + (n0 + 64 + srow) * 1024 + scolh;
    u16* as0 = &As[w * 512];
    u16* as1 = &As[2048 + w * 512];
    u16* bs0 = &Bs[w * 512];
    u16* bs1 = &Bs[2048 + w * 512];

    for (int kt = 0; kt < 32; ++kt) {
        const int ko = kt * 32;
        gl_lds16(a0 + ko, as0);
        gl_lds16(a1 + ko, as1);
        gl_lds16(b0 + ko, bs0);
        gl_lds16(b1 + ko, bs1);
        __syncthreads();
        bf16x8 af[4], bfr[4];
#pragma unroll
        for (int m = 0; m < 4; ++m)
            af[m] = *(const bf16x8*)&As[(wr * 64 + m * 16 + lr) * 32 + lg * 8];
#pragma unroll
        for (int n = 0; n < 4; ++n)
            bfr[n] = *(const bf16x8*)&Bs[(wc * 64 + n * 16 + lr) * 32 + lg * 8];
#pragma unroll
        for (int m = 0; m < 4; ++m)
#pragma unroll
            for (int n = 0; n < 4; ++n)
                acc[m][n] = mfma16(af[m], bfr[n], acc[m][n]);
        __syncthreads();
    }
}

// ---------------------------------------------------------------------------
// QKV GEMM + bias(f32), scatter to Q[B,H,T,D], K[B,H,T,D], Vt[B,H,D,T] bf16
// ---------------------------------------------------------------------------
__global__ __launch_bounds__(256) void k_gemm_qkv(const u16* __restrict__ X,
                                                  const u16* __restrict__ Wt,
                                                  const float* __restrict__ bias,
                                                  u16* __restrict__ Qo,
                                                  u16* __restrict__ Ko,
                                                  u16* __restrict__ Vto) {
    f32x4 acc[4][4];
#pragma unroll
    for (int m = 0; m < 4; ++m)
#pragma unroll
        for (int n = 0; n < 4; ++n) acc[m][n] = (f32x4){0.f, 0.f, 0.f, 0.f};
    const int n0 = blockIdx.x * 128, m0 = blockIdx.y * 128;
    gemm_tile(X, Wt, m0, n0, acc);

    const int tid = threadIdx.x, l = tid & 63, w = tid >> 6;
    const int wr = w >> 1, wc = w & 1, lr = l & 15, lg = l >> 4;
#pragma unroll
    for (int n = 0; n < 4; ++n) {
        const int c = n0 + wc * 64 + n * 16 + lr;
        const float bv = bias[c];
        const int which = c >> 10, cc = c & 1023, h = cc >> 6, d = cc & 63;
#pragma unroll
        for (int m = 0; m < 4; ++m) {
            const int rbase = m0 + wr * 64 + m * 16 + lg * 4;
#pragma unroll
            for (int j = 0; j < 4; ++j) {
                const int r = rbase + j;
                const int b = r >> 11, t = r & 2047;
                const int bh = b * NH + h;
                const u16 o = f2bf(acc[m][n][j] + bv);
                if (which == 0)      Qo[(bh * TT + t) * DD + d] = o;
                else if (which == 1) Ko[(bh * TT + t) * DD + d] = o;
                else                 Vto[(bh * DD + d) * TT + t] = o;
            }
        }
    }
}

// ---------------------------------------------------------------------------
// Proj GEMM + bias(f32) -> out f32 [8192][1024]
// ---------------------------------------------------------------------------
__global__ __launch_bounds__(256) void k_gemm_proj(const u16* __restrict__ Yin,
                                                   const u16* __restrict__ Wt,
                                                   const float* __restrict__ bias,
                                                   float* __restrict__ out) {
    f32x4 acc[4][4];
#pragma unroll
    for (int m = 0; m < 4; ++m)
#pragma unroll
        for (int n = 0; n < 4; ++n) acc[m][n] = (f32x4){0.f, 0.f, 0.f, 0.f};
    const int n0 = blockIdx.x * 128, m0 = blockIdx.y * 128;
    gemm_tile(Yin, Wt, m0, n0, acc);

    const int tid = threadIdx.x, l = tid & 63, w = tid >> 6;
    const int wr = w >> 1, wc = w & 1, lr = l & 15, lg = l >> 4;
#pragma unroll
    for (int n = 0; n < 4; ++n) {
        const int c = n0 + wc * 64 + n * 16 + lr;
        const float bv = bias[c];
#pragma unroll
        for (int m = 0; m < 4; ++m) {
            const int rbase = m0 + wr * 64 + m * 16 + lg * 4;
#pragma unroll
            for (int j = 0; j < 4; ++j) {
                const int r = rbase + j;
                out[r * CC + c] = acc[m][n][j] + bv;
            }
        }
    }
}

// ---------------------------------------------------------------------------
// Causal flash attention.  One block per (128 q rows, bh).  4 waves x 32 rows.
// kv tiles of 64.  Q,K staged [rows][64] bf16, V staged from Vt as [d][kv].
// XOR swizzle (byte ^= (row&7)<<4) applied on BOTH the global source of
// global_load_lds (linear dest) and the ds_read side (rule #21).
// ---------------------------------------------------------------------------
__global__ __launch_bounds__(256) void k_attn(const u16* __restrict__ Qg_,
                                              const u16* __restrict__ Kg_,
                                              const u16* __restrict__ Vg_,
                                              u16* __restrict__ Y) {
    __shared__ __align__(16) u16 Qs[128 * 64];
    __shared__ __align__(16) u16 Ks[64 * 64];
    __shared__ __align__(16) u16 Vs[64 * 64];
    __shared__ __align__(16) u16 Ps[4][32 * 72];   // per-wave P, stride 72 (pad)

    const int q0 = blockIdx.x * 128;
    const int bh = blockIdx.y;
    const u16* Qg = Qg_ + (size_t)bh * TT * DD;
    const u16* Kg = Kg_ + (size_t)bh * TT * DD;
    const u16* Vg = Vg_ + (size_t)bh * DD * TT;    // [64][2048]
    const int tid = threadIdx.x, l = tid & 63, w = tid >> 6;
    const int lr = l & 15, lg = l >> 4;

    // ---- stage Q tile (128 x 64), swizzled source ----
#pragma unroll
    for (int iss = 0; iss < 4; ++iss) {
        const int s = iss * 4096 + tid * 16;       // linear dest byte in tile
        const int row = s >> 7;
        const int colb = (s & 127) ^ ((row & 7) << 4);
        gl_lds16(Qg + (q0 + row) * DD + (colb >> 1), &Qs[(iss * 4096 + w * 1024) >> 1]);
    }
    __syncthreads();

    // Q fragments to registers (reused across all kv tiles)
    bf16x8 qf[2][2];
#pragma unroll
    for (int mq = 0; mq < 2; ++mq)
#pragma unroll
        for (int ks = 0; ks < 2; ++ks) {
            const int row = w * 32 + mq * 16 + lr;
            const int colb = (ks * 64 + lg * 16) ^ ((row & 7) << 4);
            qf[mq][ks] = *(const bf16x8*)&Qs[(row * 128 + colb) >> 1];
        }

    float mrun[2][4], lrun[2][4];
    f32x4 oacc[2][4];
#pragma unroll
    for (int mq = 0; mq < 2; ++mq)
#pragma unroll
        for (int j = 0; j < 4; ++j) { mrun[mq][j] = -1e30f; lrun[mq][j] = 0.f; }
#pragma unroll
    for (int mq = 0; mq < 2; ++mq)
#pragma unroll
        for (int nd = 0; nd < 4; ++nd) oacc[mq][nd] = (f32x4){0.f, 0.f, 0.f, 0.f};

    const int qw0 = q0 + w * 32;           // first q row of this wave
    const int nkv = (q0 >> 6) + 2;
    for (int it = 0; it < nkv; ++it) {
        const int kv0 = it * 64;
        // ---- stage K (kv x d) and Vt (d x kv) tiles ----
#pragma unroll
        for (int iss = 0; iss < 2; ++iss) {
            const int s = iss * 4096 + tid * 16;
            const int row = s >> 7;
            const int colb = (s & 127) ^ ((row & 7) << 4);
            gl_lds16(Kg + (kv0 + row) * DD + (colb >> 1), &Ks[(iss * 4096 + w * 1024) >> 1]);
            gl_lds16(Vg + row * TT + kv0 + (colb >> 1),   &Vs[(iss * 4096 + w * 1024) >> 1]);
        }
        __syncthreads();

        if (kv0 <= qw0 + 31) {             // wave has >=1 valid column
            // ---- S = Q K^T ----
            f32x4 sc_[2][4];
#pragma unroll
            for (int mq = 0; mq < 2; ++mq)
#pragma unroll
                for (int nk = 0; nk < 4; ++nk) sc_[mq][nk] = (f32x4){0.f, 0.f, 0.f, 0.f};
#pragma unroll
            for (int nk = 0; nk < 4; ++nk) {
#pragma unroll
                for (int ks = 0; ks < 2; ++ks) {
                    const int row = nk * 16 + lr;
                    const int colb = (ks * 64 + lg * 16) ^ ((row & 7) << 4);
                    const bf16x8 kf = *(const bf16x8*)&Ks[(row * 128 + colb) >> 1];
                    sc_[0][nk] = mfma16(qf[0][ks], kf, sc_[0][nk]);
                    sc_[1][nk] = mfma16(qf[1][ks], kf, sc_[1][nk]);
                }
            }
            // ---- scale + causal mask ----
            const bool dmask = (kv0 + 63 > qw0);
#pragma unroll
            for (int mq = 0; mq < 2; ++mq)
#pragma unroll
                for (int nk = 0; nk < 4; ++nk)
#pragma unroll
                    for (int j = 0; j < 4; ++j) {
                        float v = sc_[mq][nk][j] * 0.125f;
                        if (dmask) {
                            const int kvg = kv0 + nk * 16 + lr;
                            const int qg = qw0 + mq * 16 + lg * 4 + j;
                            if (kvg > qg) v = -1e30f;
                        }
                        sc_[mq][nk][j] = v;
                    }
            // ---- online softmax ----
#pragma unroll
            for (int mq = 0; mq < 2; ++mq) {
                float scl[4];
#pragma unroll
                for (int j = 0; j < 4; ++j) {
                    float t = fmaxf(fmaxf(sc_[mq][0][j], sc_[mq][1][j]),
                                    fmaxf(sc_[mq][2][j], sc_[mq][3][j]));
#pragma unroll
                    for (int o = 1; o < 16; o <<= 1) t = fmaxf(t, __shfl_xor(t, o));
                    const float mn = fmaxf(mrun[mq][j], t);
                    scl[j] = __expf(mrun[mq][j] - mn);
                    mrun[mq][j] = mn;
                }
                float rsum[4] = {0.f, 0.f, 0.f, 0.f};
#pragma unroll
                for (int nk = 0; nk < 4; ++nk)
#pragma unroll
                    for (int j = 0; j < 4; ++j) {
                        const float p = __expf(sc_[mq][nk][j] - mrun[mq][j]);
                        sc_[mq][nk][j] = p;
                        rsum[j] += p;
                    }
#pragma unroll
                for (int j = 0; j < 4; ++j) {
                    float t = rsum[j];
#pragma unroll
                    for (int o = 1; o < 16; o <<= 1) t += __shfl_xor(t, o);
                    lrun[mq][j] = lrun[mq][j] * scl[j] + t;
                }
#pragma unroll
                for (int nd = 0; nd < 4; ++nd)
#pragma unroll
                    for (int j = 0; j < 4; ++j) oacc[mq][nd][j] *= scl[j];
                // P -> LDS (bf16), wave-private
#pragma unroll
                for (int nk = 0; nk < 4; ++nk)
#pragma unroll
                    for (int j = 0; j < 4; ++j)
                        Ps[w][(mq * 16 + lg * 4 + j) * 72 + nk * 16 + lr] = f2bf(sc_[mq][nk][j]);
            }
            // ---- O += P V ----
#pragma unroll
            for (int ks = 0; ks < 2; ++ks) {
                const bf16x8 pa0 = *(const bf16x8*)&Ps[w][(lr) * 72 + ks * 32 + lg * 8];
                const bf16x8 pa1 = *(const bf16x8*)&Ps[w][(16 + lr) * 72 + ks * 32 + lg * 8];
#pragma unroll
                for (int nd = 0; nd < 4; ++nd) {
                    const int row = nd * 16 + lr;
                    const int colb = (ks * 64 + lg * 16) ^ ((row & 7) << 4);
                    const bf16x8 vf = *(const bf16x8*)&Vs[(row * 128 + colb) >> 1];
                    oacc[0][nd] = mfma16(pa0, vf, oacc[0][nd]);
                    oacc[1][nd] = mfma16(pa1, vf, oacc[1][nd]);
                }
            }
        }
        __syncthreads();
    }

    // ---- epilogue: Y[b, t, h*64+d] = O / l  (bf16, feeds proj GEMM) ----
    const int b = bh >> 4, h = bh & 15;
#pragma unroll
    for (int mq = 0; mq < 2; ++mq)
#pragma unroll
        for (int nd = 0; nd < 4; ++nd)
#pragma unroll
            for (int j = 0; j < 4; ++j) {
                const int t = q0 + w * 32 + mq * 16 + lg * 4 + j;
                const int d = nd * 16 + lr;
                Y[(b * TT + t) * CC + h * DD + d] = f2bf(oacc[mq][nd][j] / lrun[mq][j]);
            }
}

// ---------------------------------------------------------------------------
extern "C" void kernel_launch(void* const* d_in, const int* in_sizes, int n_in,
                              void* d_out, int out_size, void* d_ws, size_t ws_size,
                              hipStream_t stream) {
    const float* X  = (const float*)d_in[0];   // [4,2048,1024] f32
    const float* Wa = (const float*)d_in[1];   // [1024,3072]  f32
    const float* ba = (const float*)d_in[2];   // [3072]       f32
    const float* Wp = (const float*)d_in[3];   // [1024,1024]  f32
    const float* bp = (const float*)d_in[4];   // [1024]       f32
    float* out = (float*)d_out;                // [8192,1024]  f32

    u16* ws  = (u16*)d_ws;
    u16* Xb  = ws;                                    // 8192*1024
    u16* WtA = Xb + (size_t)MROWS * CC;               // 3072*1024
    u16* WtP = WtA + 3072 * 1024;                     // 1024*1024
    u16* Qb  = WtP + 1024 * 1024;                     // 64*2048*64
    u16* Kb  = Qb + (size_t)BHH * TT * DD;
    u16* Vtb = Kb + (size_t)BHH * TT * DD;
    u16* Yb  = Vtb + (size_t)BHH * TT * DD;           // 8192*1024

    k_f2b<<<dim3(MROWS * CC / 1024), 256, 0, stream>>>(X, Xb, MROWS * CC);
    k_transpose_cvt<<<dim3(96, 32), 256, 0, stream>>>(Wa, WtA, 1024, 3072);
    k_transpose_cvt<<<dim3(32, 32), 256, 0, stream>>>(Wp, WtP, 1024, 1024);
    k_gemm_qkv<<<dim3(24, 64), 256, 0, stream>>>(Xb, WtA, ba, Qb, Kb, Vtb);
    k_attn<<<dim3(16, 64), 256, 0, stream>>>(Qb, Kb, Vtb, Yb);
    k_gemm_proj<<<dim3(8, 64), 256, 0, stream>>>(Yb, WtP, bp, out);
}

// Round 3
// 273.279 us; speedup vs baseline: 1.2973x; 1.2973x over previous
//
#include <hip/hip_runtime.h>
#include <stdint.h>

// Problem constants
#define NB 4
#define TT 2048
#define CC 1024
#define NH 16
#define DD 64
#define BHH (NB*NH)     // 64 (b,h) pairs
#define MROWS (NB*TT)   // 8192

typedef uint16_t u16;
typedef __bf16 bf16x8 __attribute__((ext_vector_type(8)));
typedef float f32x4 __attribute__((ext_vector_type(4)));

__device__ __forceinline__ u16 f2bf(float f) {
    union { float f; uint32_t u; } v; v.f = f;
    uint32_t u = v.u;
    return (u16)((u + 0x7FFF + ((u >> 16) & 1)) >> 16);   // RNE
}

__device__ __forceinline__ void gl_lds16(const u16* g, u16* l) {
    // async global->LDS, 16B per lane; LDS dest is wave-uniform base + lane*16
    __builtin_amdgcn_global_load_lds(
        (const __attribute__((address_space(1))) unsigned int*)g,
        (__attribute__((address_space(3))) unsigned int*)l, 16, 0, 0);
}

__device__ __forceinline__ f32x4 mfma16(bf16x8 a, bf16x8 b, f32x4 c) {
    return __builtin_amdgcn_mfma_f32_16x16x32_bf16(a, b, c, 0, 0, 0);
}

// ---------------------------------------------------------------------------
// f32 -> bf16 elementwise convert (vectorized), n % 1024 == 0
// ---------------------------------------------------------------------------
__global__ __launch_bounds__(256) void k_f2b(const float* __restrict__ in,
                                             u16* __restrict__ out, int n) {
    const int i = (blockIdx.x * 256 + threadIdx.x) * 4;
    if (i >= n) return;
    const float4 v = *(const float4*)(in + i);
    ushort4 o;
    o.x = f2bf(v.x); o.y = f2bf(v.y); o.z = f2bf(v.z); o.w = f2bf(v.w);
    *(ushort4*)(out + i) = o;
}

// ---------------------------------------------------------------------------
// Weight transpose + convert: in f32 [R][N] -> out bf16 [N][R]
// ---------------------------------------------------------------------------
__global__ __launch_bounds__(256) void k_transpose_cvt(const float* __restrict__ in,
                                                       u16* __restrict__ out,
                                                       int R, int N) {
    __shared__ float t[32][33];
    const int n0 = blockIdx.x * 32, r0 = blockIdx.y * 32;
    const int c  = threadIdx.x & 31, rq = threadIdx.x >> 5;   // rq 0..7
#pragma unroll
    for (int i = 0; i < 4; ++i) {
        int r = rq + i * 8;
        t[r][c] = in[(r0 + r) * N + n0 + c];
    }
    __syncthreads();
#pragma unroll
    for (int i = 0; i < 4; ++i) {
        int r = rq + i * 8;
        out[(n0 + r) * R + r0 + c] = f2bf(t[c][r]);
    }
}

// ---------------------------------------------------------------------------
// GEMM core (m97 structure): C_tile[128x128] = A[128xK] * Bt[128xK]^T
// ---------------------------------------------------------------------------
__device__ __forceinline__ void gemm_tile(const u16* __restrict__ A,
                                          const u16* __restrict__ Bt,
                                          int m0, int n0, f32x4 acc[4][4]) {
    __shared__ __align__(16) u16 As[128 * 32];
    __shared__ __align__(16) u16 Bs[128 * 32];
    const int tid = threadIdx.x;
    const int l = tid & 63, w = tid >> 6;
    const int wr = w >> 1, wc = w & 1;
    const int lr = l & 15, lg = l >> 4;
    const int srow = tid >> 2;            // 0..63
    const int scolh = (tid & 3) << 3;     // ushort col 0,8,16,24

    const u16* a0 = A + (m0 + srow) * 1024 + scolh;
    const u16* a1 = A + (m0 + 64 + srow) * 1024 + scolh;
    const u16* b0 = Bt + (n0 + srow) * 1024 + scolh;
    const u16* b1 = Bt + (n0 + 64 + srow) * 1024 + scolh;
    u16* as0 = &As[w * 512];
    u16* as1 = &As[2048 + w * 512];
    u16* bs0 = &Bs[w * 512];
    u16* bs1 = &Bs[2048 + w * 512];

    for (int kt = 0; kt < 32; ++kt) {
        const int ko = kt * 32;
        gl_lds16(a0 + ko, as0);
        gl_lds16(a1 + ko, as1);
        gl_lds16(b0 + ko, bs0);
        gl_lds16(b1 + ko, bs1);
        __syncthreads();
        bf16x8 af[4], bfr[4];
#pragma unroll
        for (int m = 0; m < 4; ++m)
            af[m] = *(const bf16x8*)&As[(wr * 64 + m * 16 + lr) * 32 + lg * 8];
#pragma unroll
        for (int n = 0; n < 4; ++n)
            bfr[n] = *(const bf16x8*)&Bs[(wc * 64 + n * 16 + lr) * 32 + lg * 8];
#pragma unroll
        for (int m = 0; m < 4; ++m)
#pragma unroll
            for (int n = 0; n < 4; ++n)
                acc[m][n] = mfma16(af[m], bfr[n], acc[m][n]);
        __syncthreads();
    }
}

// ---------------------------------------------------------------------------
// QKV GEMM + bias(f32), scatter to Q[B,H,T,D], K[B,H,T,D], Vt[B,H,D,T] bf16
// ---------------------------------------------------------------------------
__global__ __launch_bounds__(256) void k_gemm_qkv(const u16* __restrict__ X,
                                                  const u16* __restrict__ Wt,
                                                  const float* __restrict__ bias,
                                                  u16* __restrict__ Qo,
                                                  u16* __restrict__ Ko,
                                                  u16* __restrict__ Vto) {
    f32x4 acc[4][4];
#pragma unroll
    for (int m = 0; m < 4; ++m)
#pragma unroll
        for (int n = 0; n < 4; ++n) acc[m][n] = (f32x4){0.f, 0.f, 0.f, 0.f};
    const int n0 = blockIdx.x * 128, m0 = blockIdx.y * 128;
    gemm_tile(X, Wt, m0, n0, acc);

    const int tid = threadIdx.x, l = tid & 63, w = tid >> 6;
    const int wr = w >> 1, wc = w & 1, lr = l & 15, lg = l >> 4;
#pragma unroll
    for (int n = 0; n < 4; ++n) {
        const int c = n0 + wc * 64 + n * 16 + lr;
        const float bv = bias[c];
        const int which = c >> 10, cc = c & 1023, h = cc >> 6, d = cc & 63;
#pragma unroll
        for (int m = 0; m < 4; ++m) {
            const int rbase = m0 + wr * 64 + m * 16 + lg * 4;
#pragma unroll
            for (int j = 0; j < 4; ++j) {
                const int r = rbase + j;
                const int b = r >> 11, t = r & 2047;
                const int bh = b * NH + h;
                const u16 o = f2bf(acc[m][n][j] + bv);
                if (which == 0)      Qo[(bh * TT + t) * DD + d] = o;
                else if (which == 1) Ko[(bh * TT + t) * DD + d] = o;
                else                 Vto[(bh * DD + d) * TT + t] = o;
            }
        }
    }
}

// ---------------------------------------------------------------------------
// Proj GEMM + bias(f32) -> out f32 [8192][1024]
// ---------------------------------------------------------------------------
__global__ __launch_bounds__(256) void k_gemm_proj(const u16* __restrict__ Yin,
                                                   const u16* __restrict__ Wt,
                                                   const float* __restrict__ bias,
                                                   float* __restrict__ out) {
    f32x4 acc[4][4];
#pragma unroll
    for (int m = 0; m < 4; ++m)
#pragma unroll
        for (int n = 0; n < 4; ++n) acc[m][n] = (f32x4){0.f, 0.f, 0.f, 0.f};
    const int n0 = blockIdx.x * 128, m0 = blockIdx.y * 128;
    gemm_tile(Yin, Wt, m0, n0, acc);

    const int tid = threadIdx.x, l = tid & 63, w = tid >> 6;
    const int wr = w >> 1, wc = w & 1, lr = l & 15, lg = l >> 4;
#pragma unroll
    for (int n = 0; n < 4; ++n) {
        const int c = n0 + wc * 64 + n * 16 + lr;
        const float bv = bias[c];
#pragma unroll
        for (int m = 0; m < 4; ++m) {
            const int rbase = m0 + wr * 64 + m * 16 + lg * 4;
#pragma unroll
            for (int j = 0; j < 4; ++j) {
                const int r = rbase + j;
                out[r * CC + c] = acc[m][n][j] + bv;
            }
        }
    }
}

// ---------------------------------------------------------------------------
// Causal flash attention v2.
//  - 1-D grid: id -> qi = 15 - id/64 (work-descending), bh = id%64
//    (64 % 8 == 0 -> all q-blocks of one bh land on one XCD: K/V L2 reuse)
//  - K/V double-buffered in LDS; stage(t+1) issued BEFORE compute(t); one
//    barrier per tile (T3 minimum recipe)
//  - Q fragments loaded global->reg once (no Q LDS, no Q barrier)
//  - softmax in exp2 domain, scale folded into constant (fma+v_exp per elem)
//  - per-fragment causal skip on diagonal tiles (QK MFMA, exp, PV ks-half)
// ---------------------------------------------------------------------------
#define PST 68   // Ps row stride (u16): conflict-free (lr*34 mod 32 distinct)

__global__ __launch_bounds__(256) void k_attn(const u16* __restrict__ Qg_,
                                              const u16* __restrict__ Kg_,
                                              const u16* __restrict__ Vg_,
                                              u16* __restrict__ Y) {
    __shared__ __align__(16) u16 Ks[2][64 * 64];
    __shared__ __align__(16) u16 Vs[2][64 * 64];
    __shared__ __align__(16) u16 Ps[4][32 * PST];

    const int id = blockIdx.x;
    const int qi = 15 - (id >> 6);
    const int bh = id & 63;
    const int q0 = qi * 128;
    const u16* Qg = Qg_ + (size_t)bh * TT * DD;
    const u16* Kg = Kg_ + (size_t)bh * TT * DD;
    const u16* Vg = Vg_ + (size_t)bh * DD * TT;    // [64][2048]
    const int tid = threadIdx.x, l = tid & 63, w = tid >> 6;
    const int lr = l & 15, lg = l >> 4;
    const int qw0 = q0 + w * 32;
    const int nkv = 2 * qi + 2;

    // ---- Q fragments straight to registers (one-time) ----
    bf16x8 qf[2][2];
#pragma unroll
    for (int mq = 0; mq < 2; ++mq)
#pragma unroll
        for (int ks = 0; ks < 2; ++ks)
            qf[mq][ks] = *(const bf16x8*)&Qg[(qw0 + mq * 16 + lr) * DD + ks * 32 + lg * 8];

    float mrun[2][4], lrun[2][4];
    f32x4 oacc[2][4];
#pragma unroll
    for (int mq = 0; mq < 2; ++mq)
#pragma unroll
        for (int j = 0; j < 4; ++j) { mrun[mq][j] = -1e30f; lrun[mq][j] = 0.f; }
#pragma unroll
    for (int mq = 0; mq < 2; ++mq)
#pragma unroll
        for (int nd = 0; nd < 4; ++nd) oacc[mq][nd] = (f32x4){0.f, 0.f, 0.f, 0.f};

    // ---- stage K/V tile `it` into buffer b (swizzled source, linear dest) ----
    auto stage = [&](int it, int b) {
        const int kv0 = it * 64;
#pragma unroll
        for (int iss = 0; iss < 2; ++iss) {
            const int s = iss * 4096 + tid * 16;       // linear dest byte
            const int row = s >> 7;
            const int colb = (s & 127) ^ ((row & 7) << 4);
            const int ldsoff = (iss * 4096 + w * 1024) >> 1;
            gl_lds16(Kg + (kv0 + row) * DD + (colb >> 1), &Ks[b][ldsoff]);
            gl_lds16(Vg + row * TT + kv0 + (colb >> 1),   &Vs[b][ldsoff]);
        }
    };

    const float C2 = 0.18033688011112042f;   // 0.125 * log2(e)

    stage(0, 0);
    __syncthreads();

    for (int it = 0; it < nkv; ++it) {
        const int b = it & 1;
        if (it + 1 < nkv) stage(it + 1, b ^ 1);    // prefetch overlaps compute
        const int kv0 = it * 64;

        if (kv0 <= qw0 + 31) {                     // wave has >=1 valid column
            // per-fragment causal classification (wave-uniform)
            bool skip[2][4], msk[2][4];
#pragma unroll
            for (int mq = 0; mq < 2; ++mq)
#pragma unroll
                for (int nk = 0; nk < 4; ++nk) {
                    skip[mq][nk] = (kv0 + nk * 16) > (qw0 + mq * 16 + 15);
                    msk[mq][nk]  = (kv0 + nk * 16 + 15) > (qw0 + mq * 16);
                }

            // ---- S = Q K^T ----
            f32x4 sc_[2][4];
#pragma unroll
            for (int mq = 0; mq < 2; ++mq)
#pragma unroll
                for (int nk = 0; nk < 4; ++nk) sc_[mq][nk] = (f32x4){0.f, 0.f, 0.f, 0.f};
#pragma unroll
            for (int nk = 0; nk < 4; ++nk) {
                if (!skip[1][nk]) {                // skip[1] => skip[0]
#pragma unroll
                    for (int ks = 0; ks < 2; ++ks) {
                        const int row = nk * 16 + lr;
                        const int colb = (ks * 64 + lg * 16) ^ ((row & 7) << 4);
                        const bf16x8 kf = *(const bf16x8*)&Ks[b][(row * 128 + colb) >> 1];
                        if (!skip[0][nk]) sc_[0][nk] = mfma16(qf[0][ks], kf, sc_[0][nk]);
                        sc_[1][nk] = mfma16(qf[1][ks], kf, sc_[1][nk]);
                    }
                }
            }

            // ---- mask + online softmax (exp2 domain) ----
#pragma unroll
            for (int mq = 0; mq < 2; ++mq) {
#pragma unroll
                for (int nk = 0; nk < 4; ++nk) {
                    if (msk[mq][nk] && !skip[mq][nk]) {
                        const int kvg = kv0 + nk * 16 + lr;
#pragma unroll
                        for (int j = 0; j < 4; ++j) {
                            const int qg = qw0 + mq * 16 + lg * 4 + j;
                            if (kvg > qg) sc_[mq][nk][j] = -1e30f;
                        }
                    }
                }
                float mx[4] = {-1e30f, -1e30f, -1e30f, -1e30f};
#pragma unroll
                for (int nk = 0; nk < 4; ++nk)
                    if (!skip[mq][nk])
#pragma unroll
                        for (int j = 0; j < 4; ++j) mx[j] = fmaxf(mx[j], sc_[mq][nk][j]);
                float mn[4], sclj[4];
#pragma unroll
                for (int j = 0; j < 4; ++j) {
#pragma unroll
                    for (int o = 1; o < 16; o <<= 1) mx[j] = fmaxf(mx[j], __shfl_xor(mx[j], o));
                    mn[j] = fmaxf(mrun[mq][j], mx[j]);
                    sclj[j] = __builtin_amdgcn_exp2f((mrun[mq][j] - mn[j]) * C2);
                    mrun[mq][j] = mn[j];
                }
                float rsum[4] = {0.f, 0.f, 0.f, 0.f};
#pragma unroll
                for (int nk = 0; nk < 4; ++nk) {
                    if (!skip[mq][nk]) {
#pragma unroll
                        for (int j = 0; j < 4; ++j) {
                            const float p = __builtin_amdgcn_exp2f((sc_[mq][nk][j] - mn[j]) * C2);
                            rsum[j] += p;
                            Ps[w][(mq * 16 + lg * 4 + j) * PST + nk * 16 + lr] = f2bf(p);
                        }
                    } else {
#pragma unroll
                        for (int j = 0; j < 4; ++j)
                            Ps[w][(mq * 16 + lg * 4 + j) * PST + nk * 16 + lr] = 0;
                    }
                }
#pragma unroll
                for (int j = 0; j < 4; ++j) {
#pragma unroll
                    for (int o = 1; o < 16; o <<= 1) rsum[j] += __shfl_xor(rsum[j], o);
                    lrun[mq][j] = lrun[mq][j] * sclj[j] + rsum[j];
                }
#pragma unroll
                for (int nd = 0; nd < 4; ++nd)
#pragma unroll
                    for (int j = 0; j < 4; ++j) oacc[mq][nd][j] *= sclj[j];
            }

            // ---- O += P V  (skip kv 32..63 half when fully masked) ----
            const bool ks1 = (kv0 + 32 <= qw0 + 31);
#pragma unroll
            for (int ks = 0; ks < 2; ++ks) {
                if (ks == 1 && !ks1) continue;
                const bf16x8 pa0 = *(const bf16x8*)&Ps[w][lr * PST + ks * 32 + lg * 8];
                const bf16x8 pa1 = *(const bf16x8*)&Ps[w][(16 + lr) * PST + ks * 32 + lg * 8];
#pragma unroll
                for (int nd = 0; nd < 4; ++nd) {
                    const int row = nd * 16 + lr;
                    const int colb = (ks * 64 + lg * 16) ^ ((row & 7) << 4);
                    const bf16x8 vf = *(const bf16x8*)&Vs[b][(row * 128 + colb) >> 1];
                    oacc[0][nd] = mfma16(pa0, vf, oacc[0][nd]);
                    oacc[1][nd] = mfma16(pa1, vf, oacc[1][nd]);
                }
            }
        }
        if (it + 1 < nkv) __syncthreads();   // drains this iter's prefetch
    }

    // ---- epilogue: Y[b, t, h*64+d] = O / l  (bf16, feeds proj GEMM) ----
    const int bb = bh >> 4, h = bh & 15;
#pragma unroll
    for (int mq = 0; mq < 2; ++mq)
#pragma unroll
        for (int nd = 0; nd < 4; ++nd)
#pragma unroll
            for (int j = 0; j < 4; ++j) {
                const int t = q0 + w * 32 + mq * 16 + lg * 4 + j;
                const int d = nd * 16 + lr;
                Y[(bb * TT + t) * CC + h * DD + d] = f2bf(oacc[mq][nd][j] / lrun[mq][j]);
            }
}

// ---------------------------------------------------------------------------
extern "C" void kernel_launch(void* const* d_in, const int* in_sizes, int n_in,
                              void* d_out, int out_size, void* d_ws, size_t ws_size,
                              hipStream_t stream) {
    const float* X  = (const float*)d_in[0];   // [4,2048,1024] f32
    const float* Wa = (const float*)d_in[1];   // [1024,3072]  f32
    const float* ba = (const float*)d_in[2];   // [3072]       f32
    const float* Wp = (const float*)d_in[3];   // [1024,1024]  f32
    const float* bp = (const float*)d_in[4];   // [1024]       f32
    float* out = (float*)d_out;                // [8192,1024]  f32

    u16* ws  = (u16*)d_ws;
    u16* Xb  = ws;                                    // 8192*1024
    u16* WtA = Xb + (size_t)MROWS * CC;               // 3072*1024
    u16* WtP = WtA + 3072 * 1024;                     // 1024*1024
    u16* Qb  = WtP + 1024 * 1024;                     // 64*2048*64
    u16* Kb  = Qb + (size_t)BHH * TT * DD;
    u16* Vtb = Kb + (size_t)BHH * TT * DD;
    u16* Yb  = Vtb + (size_t)BHH * TT * DD;           // 8192*1024

    k_f2b<<<dim3(MROWS * CC / 1024), 256, 0, stream>>>(X, Xb, MROWS * CC);
    k_transpose_cvt<<<dim3(96, 32), 256, 0, stream>>>(Wa, WtA, 1024, 3072);
    k_transpose_cvt<<<dim3(32, 32), 256, 0, stream>>>(Wp, WtP, 1024, 1024);
    k_gemm_qkv<<<dim3(24, 64), 256, 0, stream>>>(Xb, WtA, ba, Qb, Kb, Vtb);
    k_attn<<<dim3(1024), 256, 0, stream>>>(Qb, Kb, Vtb, Yb);
    k_gemm_proj<<<dim3(8, 64), 256, 0, stream>>>(Yb, WtP, bp, out);
}

// Round 4
// 265.767 us; speedup vs baseline: 1.3340x; 1.0283x over previous
//
#include <hip/hip_runtime.h>
#include <stdint.h>

// Problem constants
#define NB 4
#define TT 2048
#define CC 1024
#define NH 16
#define DD 64
#define BHH (NB*NH)     // 64 (b,h) pairs
#define MROWS (NB*TT)   // 8192

typedef uint16_t u16;
typedef uint32_t u32;
typedef __bf16 bf16x8 __attribute__((ext_vector_type(8)));
typedef float f32x4 __attribute__((ext_vector_type(4)));
typedef float f32x16 __attribute__((ext_vector_type(16)));

__device__ __forceinline__ u16 f2bf(float f) {
    union { float f; uint32_t u; } v; v.f = f;
    uint32_t u = v.u;
    return (u16)((u + 0x7FFF + ((u >> 16) & 1)) >> 16);   // RNE
}

__device__ __forceinline__ u32 cvtpk(float lo, float hi) {
    u32 r;
    asm volatile("v_cvt_pk_bf16_f32 %0, %1, %2" : "=v"(r) : "v"(lo), "v"(hi));
    return r;
}

// v_permlane32_swap_b32 a, b:  a' = {a.lanes[0:31], b.lanes[0:31]},
//                              b' = {a.lanes[32:63], b.lanes[32:63]}
__device__ __forceinline__ void plswap(u32& a, u32& b) {
    asm volatile("v_permlane32_swap_b32 %0, %1" : "+v"(a), "+v"(b));
}

__device__ __forceinline__ bf16x8 mk8(u32 a, u32 b, u32 c, u32 d) {
    union { u32 u[4]; bf16x8 v; } x;
    x.u[0] = a; x.u[1] = b; x.u[2] = c; x.u[3] = d;
    return x.v;
}

__device__ __forceinline__ void gl_lds16(const u16* g, u16* l) {
    __builtin_amdgcn_global_load_lds(
        (const __attribute__((address_space(1))) unsigned int*)g,
        (__attribute__((address_space(3))) unsigned int*)l, 16, 0, 0);
}

__device__ __forceinline__ f32x4 mfma16(bf16x8 a, bf16x8 b, f32x4 c) {
    return __builtin_amdgcn_mfma_f32_16x16x32_bf16(a, b, c, 0, 0, 0);
}
__device__ __forceinline__ f32x16 mfma32(bf16x8 a, bf16x8 b, f32x16 c) {
    return __builtin_amdgcn_mfma_f32_32x32x16_bf16(a, b, c, 0, 0, 0);
}

// ---------------------------------------------------------------------------
// f32 -> bf16 elementwise convert (vectorized), n % 1024 == 0
// ---------------------------------------------------------------------------
__global__ __launch_bounds__(256) void k_f2b(const float* __restrict__ in,
                                             u16* __restrict__ out, int n) {
    const int i = (blockIdx.x * 256 + threadIdx.x) * 4;
    if (i >= n) return;
    const float4 v = *(const float4*)(in + i);
    ushort4 o;
    o.x = f2bf(v.x); o.y = f2bf(v.y); o.z = f2bf(v.z); o.w = f2bf(v.w);
    *(ushort4*)(out + i) = o;
}

// ---------------------------------------------------------------------------
// Weight transpose + convert: in f32 [R][N] -> out bf16 [N][R]
// ---------------------------------------------------------------------------
__global__ __launch_bounds__(256) void k_transpose_cvt(const float* __restrict__ in,
                                                       u16* __restrict__ out,
                                                       int R, int N) {
    __shared__ float t[32][33];
    const int n0 = blockIdx.x * 32, r0 = blockIdx.y * 32;
    const int c  = threadIdx.x & 31, rq = threadIdx.x >> 5;   // rq 0..7
#pragma unroll
    for (int i = 0; i < 4; ++i) {
        int r = rq + i * 8;
        t[r][c] = in[(r0 + r) * N + n0 + c];
    }
    __syncthreads();
#pragma unroll
    for (int i = 0; i < 4; ++i) {
        int r = rq + i * 8;
        out[(n0 + r) * R + r0 + c] = f2bf(t[c][r]);
    }
}

// ---------------------------------------------------------------------------
// GEMM core (m97 structure): C_tile[128x128] = A[128xK] * Bt[128xK]^T
// ---------------------------------------------------------------------------
__device__ __forceinline__ void gemm_tile(const u16* __restrict__ A,
                                          const u16* __restrict__ Bt,
                                          int m0, int n0, f32x4 acc[4][4]) {
    __shared__ __align__(16) u16 As[128 * 32];
    __shared__ __align__(16) u16 Bs[128 * 32];
    const int tid = threadIdx.x;
    const int l = tid & 63, w = tid >> 6;
    const int wr = w >> 1, wc = w & 1;
    const int lr = l & 15, lg = l >> 4;
    const int srow = tid >> 2;            // 0..63
    const int scolh = (tid & 3) << 3;     // ushort col 0,8,16,24

    const u16* a0 = A + (m0 + srow) * 1024 + scolh;
    const u16* a1 = A + (m0 + 64 + srow) * 1024 + scolh;
    const u16* b0 = Bt + (n0 + srow) * 1024 + scolh;
    const u16* b1 = Bt + (n0 + 64 + srow) * 1024 + scolh;
    u16* as0 = &As[w * 512];
    u16* as1 = &As[2048 + w * 512];
    u16* bs0 = &Bs[w * 512];
    u16* bs1 = &Bs[2048 + w * 512];

    for (int kt = 0; kt < 32; ++kt) {
        const int ko = kt * 32;
        gl_lds16(a0 + ko, as0);
        gl_lds16(a1 + ko, as1);
        gl_lds16(b0 + ko, bs0);
        gl_lds16(b1 + ko, bs1);
        __syncthreads();
        bf16x8 af[4], bfr[4];
#pragma unroll
        for (int m = 0; m < 4; ++m)
            af[m] = *(const bf16x8*)&As[(wr * 64 + m * 16 + lr) * 32 + lg * 8];
#pragma unroll
        for (int n = 0; n < 4; ++n)
            bfr[n] = *(const bf16x8*)&Bs[(wc * 64 + n * 16 + lr) * 32 + lg * 8];
#pragma unroll
        for (int m = 0; m < 4; ++m)
#pragma unroll
            for (int n = 0; n < 4; ++n)
                acc[m][n] = mfma16(af[m], bfr[n], acc[m][n]);
        __syncthreads();
    }
}

// ---------------------------------------------------------------------------
// QKV GEMM + bias(f32), scatter to Q[B,H,T,D], K[B,H,T,D], Vt[B,H,D,T] bf16
// ---------------------------------------------------------------------------
__global__ __launch_bounds__(256) void k_gemm_qkv(const u16* __restrict__ X,
                                                  const u16* __restrict__ Wt,
                                                  const float* __restrict__ bias,
                                                  u16* __restrict__ Qo,
                                                  u16* __restrict__ Ko,
                                                  u16* __restrict__ Vto) {
    f32x4 acc[4][4];
#pragma unroll
    for (int m = 0; m < 4; ++m)
#pragma unroll
        for (int n = 0; n < 4; ++n) acc[m][n] = (f32x4){0.f, 0.f, 0.f, 0.f};
    const int n0 = blockIdx.x * 128, m0 = blockIdx.y * 128;
    gemm_tile(X, Wt, m0, n0, acc);

    const int tid = threadIdx.x, l = tid & 63, w = tid >> 6;
    const int wr = w >> 1, wc = w & 1, lr = l & 15, lg = l >> 4;
#pragma unroll
    for (int n = 0; n < 4; ++n) {
        const int c = n0 + wc * 64 + n * 16 + lr;
        const float bv = bias[c];
        const int which = c >> 10, cc = c & 1023, h = cc >> 6, d = cc & 63;
#pragma unroll
        for (int m = 0; m < 4; ++m) {
            const int rbase = m0 + wr * 64 + m * 16 + lg * 4;
#pragma unroll
            for (int j = 0; j < 4; ++j) {
                const int r = rbase + j;
                const int b = r >> 11, t = r & 2047;
                const int bh = b * NH + h;
                const u16 o = f2bf(acc[m][n][j] + bv);
                if (which == 0)      Qo[(bh * TT + t) * DD + d] = o;
                else if (which == 1) Ko[(bh * TT + t) * DD + d] = o;
                else                 Vto[(bh * DD + d) * TT + t] = o;
            }
        }
    }
}

// ---------------------------------------------------------------------------
// Proj GEMM + bias(f32) -> out f32 [8192][1024]
// ---------------------------------------------------------------------------
__global__ __launch_bounds__(256) void k_gemm_proj(const u16* __restrict__ Yin,
                                                   const u16* __restrict__ Wt,
                                                   const float* __restrict__ bias,
                                                   float* __restrict__ out) {
    f32x4 acc[4][4];
#pragma unroll
    for (int m = 0; m < 4; ++m)
#pragma unroll
        for (int n = 0; n < 4; ++n) acc[m][n] = (f32x4){0.f, 0.f, 0.f, 0.f};
    const int n0 = blockIdx.x * 128, m0 = blockIdx.y * 128;
    gemm_tile(Yin, Wt, m0, n0, acc);

    const int tid = threadIdx.x, l = tid & 63, w = tid >> 6;
    const int wr = w >> 1, wc = w & 1, lr = l & 15, lg = l >> 4;
#pragma unroll
    for (int n = 0; n < 4; ++n) {
        const int c = n0 + wc * 64 + n * 16 + lr;
        const float bv = bias[c];
#pragma unroll
        for (int m = 0; m < 4; ++m) {
            const int rbase = m0 + wr * 64 + m * 16 + lg * 4;
#pragma unroll
            for (int j = 0; j < 4; ++j) {
                const int r = rbase + j;
                out[r * CC + c] = acc[m][n][j] + bv;
            }
        }
    }
}

// ---------------------------------------------------------------------------
// Causal flash attention v3 — swapped-operand 32x32 MFMA, register-resident.
//  - Per wave: one 32-row q strip.  S^T = mfma(K_frag, Q_frag): lane owns
//    q-column (l&31), kv rows = (r&3)+8*(r>>2)+4*(l>>5)  [m74/m101 layout]
//  - softmax fully in-register: 15 in-lane fmax + one shfl_xor(32);
//    exp2 domain with folded 1/8 scale; T13 skip of O-rescale on no-growth
//  - P -> bf16 via v_cvt_pk_bf16_f32, redistributed to PV B-fragments with
//    v_permlane32_swap_b32 (T12): zero LDS, zero barriers in the kernel
//  - K, V^T, Q fragments read directly from global (L2-resident per bh;
//    XCD-grouped grid: all q-blocks of one bh on one XCD)
// ---------------------------------------------------------------------------
__global__ __launch_bounds__(256) void k_attn(const u16* __restrict__ Qg_,
                                              const u16* __restrict__ Kg_,
                                              const u16* __restrict__ Vg_,
                                              u16* __restrict__ Y) {
    const int id = blockIdx.x;
    const int qi = 15 - (id >> 6);         // work-descending
    const int bh = id & 63;
    const int q0 = qi * 128;
    const u16* Qg = Qg_ + (size_t)bh * TT * DD;
    const u16* Kg = Kg_ + (size_t)bh * TT * DD;
    const u16* Vg = Vg_ + (size_t)bh * DD * TT;    // [64][2048]
    const int tid = threadIdx.x, l = tid & 63, w = tid >> 6;
    const int lq = l & 31, hi = l >> 5;
    const int qs = q0 + w * 32;            // this wave's strip base

    // diagonal-tile causal mask bits: reg r masked iff kv_local > q_local
    unsigned dmask = 0;
#pragma unroll
    for (int r = 0; r < 16; ++r) {
        const int kvloc = (r & 3) + 8 * (r >> 2) + 4 * hi;
        if (kvloc > lq) dmask |= (1u << r);
    }

    // Q fragments (B-operand: col=q=l&31, k=d=hi*8+j), loaded once
    const u16* qrow = Qg + (qs + lq) * DD + hi * 8;
    bf16x8 qf0 = *(const bf16x8*)(qrow);
    bf16x8 qf1 = *(const bf16x8*)(qrow + 16);
    bf16x8 qf2 = *(const bf16x8*)(qrow + 32);
    bf16x8 qf3 = *(const bf16x8*)(qrow + 48);

    f32x16 o0 = {}, o1 = {};               // O^T accum, d 0..31 / 32..63
    float mrun = -1e30f, lrun = 0.f;
    const float C2 = 0.18033688011112042f; // 0.125 * log2(e)
    const int ntiles = qs / 32 + 1;

    for (int t = 0; t < ntiles; ++t) {
        const int kv0 = t * 32;

        // ---- S^T = K Q  (A = K: row=kv=l&31, k=d) ----
        const u16* krow = Kg + (kv0 + lq) * DD + hi * 8;
        const bf16x8 kf0 = *(const bf16x8*)(krow);
        const bf16x8 kf1 = *(const bf16x8*)(krow + 16);
        const bf16x8 kf2 = *(const bf16x8*)(krow + 32);
        const bf16x8 kf3 = *(const bf16x8*)(krow + 48);
        f32x16 st = {};
        st = mfma32(kf0, qf0, st);
        st = mfma32(kf1, qf1, st);
        st = mfma32(kf2, qf2, st);
        st = mfma32(kf3, qf3, st);

        if (t == ntiles - 1) {             // diagonal tile: apply causal mask
#pragma unroll
            for (int r = 0; r < 16; ++r)
                if ((dmask >> r) & 1) st[r] = -1e30f;
        }

        // ---- row max (in-lane + partner exchange) ----
        float mx = st[0];
#pragma unroll
        for (int r = 1; r < 16; ++r) mx = fmaxf(mx, st[r]);
        mx = fmaxf(mx, __shfl_xor(mx, 32));

        if (!__all(mx <= mrun)) {          // T13: skip rescale on no-growth
            const float mn = fmaxf(mrun, mx);
            const float scl = __builtin_amdgcn_exp2f((mrun - mn) * C2);
            mrun = mn;
            lrun *= scl;
#pragma unroll
            for (int r = 0; r < 16; ++r) { o0[r] *= scl; o1[r] *= scl; }
        }

        // ---- P = exp2((S - m) * C2), pack to bf16 pairs ----
        float psum = 0.f;
        u32 pk0, pk1, pk2, pk3, pk4, pk5, pk6, pk7;
        {
            float pa, pb;
            pa = __builtin_amdgcn_exp2f((st[0] - mrun) * C2);
            pb = __builtin_amdgcn_exp2f((st[1] - mrun) * C2);
            psum += pa + pb; pk0 = cvtpk(pa, pb);
            pa = __builtin_amdgcn_exp2f((st[2] - mrun) * C2);
            pb = __builtin_amdgcn_exp2f((st[3] - mrun) * C2);
            psum += pa + pb; pk1 = cvtpk(pa, pb);
            pa = __builtin_amdgcn_exp2f((st[4] - mrun) * C2);
            pb = __builtin_amdgcn_exp2f((st[5] - mrun) * C2);
            psum += pa + pb; pk2 = cvtpk(pa, pb);
            pa = __builtin_amdgcn_exp2f((st[6] - mrun) * C2);
            pb = __builtin_amdgcn_exp2f((st[7] - mrun) * C2);
            psum += pa + pb; pk3 = cvtpk(pa, pb);
            pa = __builtin_amdgcn_exp2f((st[8] - mrun) * C2);
            pb = __builtin_amdgcn_exp2f((st[9] - mrun) * C2);
            psum += pa + pb; pk4 = cvtpk(pa, pb);
            pa = __builtin_amdgcn_exp2f((st[10] - mrun) * C2);
            pb = __builtin_amdgcn_exp2f((st[11] - mrun) * C2);
            psum += pa + pb; pk5 = cvtpk(pa, pb);
            pa = __builtin_amdgcn_exp2f((st[12] - mrun) * C2);
            pb = __builtin_amdgcn_exp2f((st[13] - mrun) * C2);
            psum += pa + pb; pk6 = cvtpk(pa, pb);
            pa = __builtin_amdgcn_exp2f((st[14] - mrun) * C2);
            pb = __builtin_amdgcn_exp2f((st[15] - mrun) * C2);
            psum += pa + pb; pk7 = cvtpk(pa, pb);
        }
        lrun += psum;

        // ---- redistribute to PV B-fragments (T12 permlane32_swap) ----
        plswap(pk0, pk2); plswap(pk1, pk3);
        plswap(pk4, pk6); plswap(pk5, pk7);
        const bf16x8 pf0 = mk8(pk0, pk1, pk2, pk3);   // kv 0..15 slice
        const bf16x8 pf1 = mk8(pk4, pk5, pk6, pk7);   // kv 16..31 slice

        // ---- O^T += V^T P  (A = V^T: row=d=l&31, k=kv) ----
        const u16* vrow = Vg + lq * TT + kv0 + hi * 8;
        o0 = mfma32(*(const bf16x8*)(vrow),            pf0, o0);
        o0 = mfma32(*(const bf16x8*)(vrow + 16),       pf1, o0);
        o1 = mfma32(*(const bf16x8*)(vrow + 32 * TT),      pf0, o1);
        o1 = mfma32(*(const bf16x8*)(vrow + 32 * TT + 16), pf1, o1);
    }

    // ---- epilogue: combine partner sums, write Y row (one q per lane) ----
    lrun += __shfl_xor(lrun, 32);
    const float inv = 1.0f / lrun;
    const int bb = bh >> 4, h = bh & 15;
    u16* yrow = Y + (size_t)(bb * TT + qs + lq) * CC + h * DD;
#pragma unroll
    for (int rq = 0; rq < 4; ++rq) {
        const int d0 = 8 * rq + 4 * hi;
        const u32 w0 = cvtpk(o0[rq * 4 + 0] * inv, o0[rq * 4 + 1] * inv);
        const u32 w1 = cvtpk(o0[rq * 4 + 2] * inv, o0[rq * 4 + 3] * inv);
        *(uint2*)&yrow[d0] = make_uint2(w0, w1);
        const u32 w2 = cvtpk(o1[rq * 4 + 0] * inv, o1[rq * 4 + 1] * inv);
        const u32 w3 = cvtpk(o1[rq * 4 + 2] * inv, o1[rq * 4 + 3] * inv);
        *(uint2*)&yrow[32 + d0] = make_uint2(w2, w3);
    }
}

// ---------------------------------------------------------------------------
extern "C" void kernel_launch(void* const* d_in, const int* in_sizes, int n_in,
                              void* d_out, int out_size, void* d_ws, size_t ws_size,
                              hipStream_t stream) {
    const float* X  = (const float*)d_in[0];   // [4,2048,1024] f32
    const float* Wa = (const float*)d_in[1];   // [1024,3072]  f32
    const float* ba = (const float*)d_in[2];   // [3072]       f32
    const float* Wp = (const float*)d_in[3];   // [1024,1024]  f32
    const float* bp = (const float*)d_in[4];   // [1024]       f32
    float* out = (float*)d_out;                // [8192,1024]  f32

    u16* ws  = (u16*)d_ws;
    u16* Xb  = ws;                                    // 8192*1024
    u16* WtA = Xb + (size_t)MROWS * CC;               // 3072*1024
    u16* WtP = WtA + 3072 * 1024;                     // 1024*1024
    u16* Qb  = WtP + 1024 * 1024;                     // 64*2048*64
    u16* Kb  = Qb + (size_t)BHH * TT * DD;
    u16* Vtb = Kb + (size_t)BHH * TT * DD;
    u16* Yb  = Vtb + (size_t)BHH * TT * DD;           // 8192*1024

    k_f2b<<<dim3(MROWS * CC / 1024), 256, 0, stream>>>(X, Xb, MROWS * CC);
    k_transpose_cvt<<<dim3(96, 32), 256, 0, stream>>>(Wa, WtA, 1024, 3072);
    k_transpose_cvt<<<dim3(32, 32), 256, 0, stream>>>(Wp, WtP, 1024, 1024);
    k_gemm_qkv<<<dim3(24, 64), 256, 0, stream>>>(Xb, WtA, ba, Qb, Kb, Vtb);
    k_attn<<<dim3(1024), 256, 0, stream>>>(Qb, Kb, Vtb, Yb);
    k_gemm_proj<<<dim3(8, 64), 256, 0, stream>>>(Yb, WtP, bp, out);
}

// Round 5
// 205.502 us; speedup vs baseline: 1.7252x; 1.2933x over previous
//
#include <hip/hip_runtime.h>
#include <stdint.h>

// Problem constants
#define NB 4
#define TT 2048
#define CC 1024
#define NH 16
#define DD 64
#define BHH (NB*NH)     // 64 (b,h) pairs
#define MROWS (NB*TT)   // 8192

typedef uint16_t u16;
typedef uint32_t u32;
typedef __bf16 bf16x8 __attribute__((ext_vector_type(8)));
typedef float f32x4 __attribute__((ext_vector_type(4)));
typedef float f32x16 __attribute__((ext_vector_type(16)));

__device__ __forceinline__ u16 f2bf(float f) {
    union { float f; uint32_t u; } v; v.f = f;
    uint32_t u = v.u;
    return (u16)((u + 0x7FFF + ((u >> 16) & 1)) >> 16);   // RNE
}

__device__ __forceinline__ u32 cvtpk(float lo, float hi) {
    u32 r;
    asm volatile("v_cvt_pk_bf16_f32 %0, %1, %2" : "=v"(r) : "v"(lo), "v"(hi));
    return r;
}

// v_permlane32_swap_b32 a, b:  a' = {a.lanes[0:31], b.lanes[0:31]},
//                              b' = {a.lanes[32:63], b.lanes[32:63]}
__device__ __forceinline__ void plswap(u32& a, u32& b) {
    asm volatile("v_permlane32_swap_b32 %0, %1" : "+v"(a), "+v"(b));
}

__device__ __forceinline__ bf16x8 mk8(u32 a, u32 b, u32 c, u32 d) {
    union { u32 u[4]; bf16x8 v; } x;
    x.u[0] = a; x.u[1] = b; x.u[2] = c; x.u[3] = d;
    return x.v;
}

__device__ __forceinline__ void gl_lds16(const u16* g, u16* l) {
    __builtin_amdgcn_global_load_lds(
        (const __attribute__((address_space(1))) unsigned int*)g,
        (__attribute__((address_space(3))) unsigned int*)l, 16, 0, 0);
}

__device__ __forceinline__ f32x4 mfma16(bf16x8 a, bf16x8 b, f32x4 c) {
    return __builtin_amdgcn_mfma_f32_16x16x32_bf16(a, b, c, 0, 0, 0);
}
__device__ __forceinline__ f32x16 mfma32(bf16x8 a, bf16x8 b, f32x16 c) {
    return __builtin_amdgcn_mfma_f32_32x32x16_bf16(a, b, c, 0, 0, 0);
}

// ---------------------------------------------------------------------------
// f32 -> bf16 elementwise convert (vectorized), n % 1024 == 0
// ---------------------------------------------------------------------------
__global__ __launch_bounds__(256) void k_f2b(const float* __restrict__ in,
                                             u16* __restrict__ out, int n) {
    const int i = (blockIdx.x * 256 + threadIdx.x) * 4;
    if (i >= n) return;
    const float4 v = *(const float4*)(in + i);
    ushort4 o;
    o.x = f2bf(v.x); o.y = f2bf(v.y); o.z = f2bf(v.z); o.w = f2bf(v.w);
    *(ushort4*)(out + i) = o;
}

// ---------------------------------------------------------------------------
// Weight transpose + convert: in f32 [R][N] -> out bf16 [N][R]
// ---------------------------------------------------------------------------
__global__ __launch_bounds__(256) void k_transpose_cvt(const float* __restrict__ in,
                                                       u16* __restrict__ out,
                                                       int R, int N) {
    __shared__ float t[32][33];
    const int n0 = blockIdx.x * 32, r0 = blockIdx.y * 32;
    const int c  = threadIdx.x & 31, rq = threadIdx.x >> 5;   // rq 0..7
#pragma unroll
    for (int i = 0; i < 4; ++i) {
        int r = rq + i * 8;
        t[r][c] = in[(r0 + r) * N + n0 + c];
    }
    __syncthreads();
#pragma unroll
    for (int i = 0; i < 4; ++i) {
        int r = rq + i * 8;
        out[(n0 + r) * R + r0 + c] = f2bf(t[c][r]);
    }
}

// ---------------------------------------------------------------------------
// GEMM core (m97 structure): C_tile[128x128] = A[128xK] * Bt[128xK]^T
// ---------------------------------------------------------------------------
__device__ __forceinline__ void gemm_tile(const u16* __restrict__ A,
                                          const u16* __restrict__ Bt,
                                          int m0, int n0, f32x4 acc[4][4]) {
    __shared__ __align__(16) u16 As[128 * 32];
    __shared__ __align__(16) u16 Bs[128 * 32];
    const int tid = threadIdx.x;
    const int l = tid & 63, w = tid >> 6;
    const int wr = w >> 1, wc = w & 1;
    const int lr = l & 15, lg = l >> 4;
    const int srow = tid >> 2;            // 0..63
    const int scolh = (tid & 3) << 3;     // ushort col 0,8,16,24

    const u16* a0 = A + (m0 + srow) * 1024 + scolh;
    const u16* a1 = A + (m0 + 64 + srow) * 1024 + scolh;
    const u16* b0 = Bt + (n0 + srow) * 1024 + scolh;
    const u16* b1 = Bt + (n0 + 64 + srow) * 1024 + scolh;
    u16* as0 = &As[w * 512];
    u16* as1 = &As[2048 + w * 512];
    u16* bs0 = &Bs[w * 512];
    u16* bs1 = &Bs[2048 + w * 512];

    for (int kt = 0; kt < 32; ++kt) {
        const int ko = kt * 32;
        gl_lds16(a0 + ko, as0);
        gl_lds16(a1 + ko, as1);
        gl_lds16(b0 + ko, bs0);
        gl_lds16(b1 + ko, bs1);
        __syncthreads();
        bf16x8 af[4], bfr[4];
#pragma unroll
        for (int m = 0; m < 4; ++m)
            af[m] = *(const bf16x8*)&As[(wr * 64 + m * 16 + lr) * 32 + lg * 8];
#pragma unroll
        for (int n = 0; n < 4; ++n)
            bfr[n] = *(const bf16x8*)&Bs[(wc * 64 + n * 16 + lr) * 32 + lg * 8];
#pragma unroll
        for (int m = 0; m < 4; ++m)
#pragma unroll
            for (int n = 0; n < 4; ++n)
                acc[m][n] = mfma16(af[m], bfr[n], acc[m][n]);
        __syncthreads();
    }
}

// ---------------------------------------------------------------------------
// QKV GEMM + bias(f32), scatter to Q[B,H,T,D], K[B,H,T,D], Vt[B,H,D,T] bf16
// ---------------------------------------------------------------------------
__global__ __launch_bounds__(256) void k_gemm_qkv(const u16* __restrict__ X,
                                                  const u16* __restrict__ Wt,
                                                  const float* __restrict__ bias,
                                                  u16* __restrict__ Qo,
                                                  u16* __restrict__ Ko,
                                                  u16* __restrict__ Vto) {
    f32x4 acc[4][4];
#pragma unroll
    for (int m = 0; m < 4; ++m)
#pragma unroll
        for (int n = 0; n < 4; ++n) acc[m][n] = (f32x4){0.f, 0.f, 0.f, 0.f};
    const int n0 = blockIdx.x * 128, m0 = blockIdx.y * 128;
    gemm_tile(X, Wt, m0, n0, acc);

    const int tid = threadIdx.x, l = tid & 63, w = tid >> 6;
    const int wr = w >> 1, wc = w & 1, lr = l & 15, lg = l >> 4;
#pragma unroll
    for (int n = 0; n < 4; ++n) {
        const int c = n0 + wc * 64 + n * 16 + lr;
        const float bv = bias[c];
        const int which = c >> 10, cc = c & 1023, h = cc >> 6, d = cc & 63;
#pragma unroll
        for (int m = 0; m < 4; ++m) {
            const int rbase = m0 + wr * 64 + m * 16 + lg * 4;
#pragma unroll
            for (int j = 0; j < 4; ++j) {
                const int r = rbase + j;
                const int b = r >> 11, t = r & 2047;
                const int bh = b * NH + h;
                const u16 o = f2bf(acc[m][n][j] + bv);
                if (which == 0)      Qo[(bh * TT + t) * DD + d] = o;
                else if (which == 1) Ko[(bh * TT + t) * DD + d] = o;
                else                 Vto[(bh * DD + d) * TT + t] = o;
            }
        }
    }
}

// ---------------------------------------------------------------------------
// Proj GEMM + bias(f32) -> out f32 [8192][1024]
// ---------------------------------------------------------------------------
__global__ __launch_bounds__(256) void k_gemm_proj(const u16* __restrict__ Yin,
                                                   const u16* __restrict__ Wt,
                                                   const float* __restrict__ bias,
                                                   float* __restrict__ out) {
    f32x4 acc[4][4];
#pragma unroll
    for (int m = 0; m < 4; ++m)
#pragma unroll
        for (int n = 0; n < 4; ++n) acc[m][n] = (f32x4){0.f, 0.f, 0.f, 0.f};
    const int n0 = blockIdx.x * 128, m0 = blockIdx.y * 128;
    gemm_tile(Yin, Wt, m0, n0, acc);

    const int tid = threadIdx.x, l = tid & 63, w = tid >> 6;
    const int wr = w >> 1, wc = w & 1, lr = l & 15, lg = l >> 4;
#pragma unroll
    for (int n = 0; n < 4; ++n) {
        const int c = n0 + wc * 64 + n * 16 + lr;
        const float bv = bias[c];
#pragma unroll
        for (int m = 0; m < 4; ++m) {
            const int rbase = m0 + wr * 64 + m * 16 + lg * 4;
#pragma unroll
            for (int j = 0; j < 4; ++j) {
                const int r = rbase + j;
                out[r * CC + c] = acc[m][n][j] + bv;
            }
        }
    }
}

// ---------------------------------------------------------------------------
// Causal flash attention v4 — swapped-operand 32x32 MFMA register softmax
// (round-4 structure) + LDS-staged K/V tiles (round-3 staging).
//  - kv tiles of 64: K tile [64 kv][128B], V^T tile [64 d][128B] in LDS,
//    double-buffered; coalesced global_load_lds with XOR swizzle
//    byte^=((row&7)<<4) on BOTH source and ds_read side (rule #21).
//  - stage(t+1) issued before compute(t); one barrier per tile.
//  - per wave: 32-row q strip; S^T = mfma32(K,Q); softmax in-register
//    (15 fmax + shfl_xor(32)); P->bf16 cvt_pk + permlane32_swap (T12);
//    T13 rescale skip.  Two 32-kv sub-steps per tile; diagonal mask on the
//    kvs==qs sub-step; sub-steps with kvs>qs skipped.
// ---------------------------------------------------------------------------
__global__ __launch_bounds__(256) void k_attn(const u16* __restrict__ Qg_,
                                              const u16* __restrict__ Kg_,
                                              const u16* __restrict__ Vg_,
                                              u16* __restrict__ Y) {
    __shared__ __align__(16) u16 Ks[2][64 * 64];
    __shared__ __align__(16) u16 Vs[2][64 * 64];

    const int id = blockIdx.x;
    const int qi = 15 - (id >> 6);         // work-descending
    const int bh = id & 63;
    const int q0 = qi * 128;
    const u16* Qg = Qg_ + (size_t)bh * TT * DD;
    const u16* Kg = Kg_ + (size_t)bh * TT * DD;
    const u16* Vg = Vg_ + (size_t)bh * DD * TT;    // [64][2048]
    const int tid = threadIdx.x, l = tid & 63, w = tid >> 6;
    const int lq = l & 31, hi = l >> 5;
    const int qs = q0 + w * 32;            // this wave's strip base

    // diagonal-tile causal mask bits: reg r masked iff kv_local > q_local
    unsigned dmask = 0;
#pragma unroll
    for (int r = 0; r < 16; ++r) {
        const int kvloc = (r & 3) + 8 * (r >> 2) + 4 * hi;
        if (kvloc > lq) dmask |= (1u << r);
    }

    // Q fragments (B-operand: col=q=l&31, k=d=hi*8+j), loaded once
    const u16* qrow = Qg + (qs + lq) * DD + hi * 8;
    bf16x8 qf0 = *(const bf16x8*)(qrow);
    bf16x8 qf1 = *(const bf16x8*)(qrow + 16);
    bf16x8 qf2 = *(const bf16x8*)(qrow + 32);
    bf16x8 qf3 = *(const bf16x8*)(qrow + 48);

    f32x16 o0 = {}, o1 = {};               // O^T accum, d 0..31 / 32..63
    float mrun = -1e30f, lrun = 0.f;
    const float C2 = 0.18033688011112042f; // 0.125 * log2(e)
    const int nt = 2 * qi + 2;             // block-level 64-kv tiles

    // stage K/V 64-kv tile `t` into buffer b (swizzled source, linear dest)
    auto stage = [&](int t, int b) {
        const int kv0 = t * 64;
#pragma unroll
        for (int iss = 0; iss < 2; ++iss) {
            const int s = iss * 4096 + tid * 16;       // linear dest byte
            const int row = s >> 7;
            const int colb = (s & 127) ^ ((row & 7) << 4);
            const int ldsoff = (iss * 4096 + w * 1024) >> 1;
            gl_lds16(Kg + (kv0 + row) * DD + (colb >> 1), &Ks[b][ldsoff]);
            gl_lds16(Vg + row * TT + kv0 + (colb >> 1),   &Vs[b][ldsoff]);
        }
    };

    stage(0, 0);
    __syncthreads();

    for (int t = 0; t < nt; ++t) {
        const int b = t & 1;
        if (t + 1 < nt) stage(t + 1, b ^ 1);   // prefetch overlaps compute
        const int kv0 = t * 64;

#pragma unroll
        for (int s = 0; s < 2; ++s) {
            const int kvs = kv0 + 32 * s;
            if (kvs > qs) continue;            // wave-uniform

            // ---- S^T = K Q from LDS (A = K: row=kv, k=d) ----
            f32x16 st = {};
#pragma unroll
            for (int i = 0; i < 4; ++i) {
                const int row = 32 * s + lq;
                const int byte = (32 * i + 16 * hi) ^ ((row & 7) << 4);
                const bf16x8 kf = *(const bf16x8*)&Ks[b][(row * 128 + byte) >> 1];
                if (i == 0) st = mfma32(kf, qf0, st);
                else if (i == 1) st = mfma32(kf, qf1, st);
                else if (i == 2) st = mfma32(kf, qf2, st);
                else st = mfma32(kf, qf3, st);
            }

            if (kvs == qs) {                   // diagonal: causal mask
#pragma unroll
                for (int r = 0; r < 16; ++r)
                    if ((dmask >> r) & 1) st[r] = -1e30f;
            }

            // ---- row max (in-lane + partner exchange) ----
            float mx = st[0];
#pragma unroll
            for (int r = 1; r < 16; ++r) mx = fmaxf(mx, st[r]);
            mx = fmaxf(mx, __shfl_xor(mx, 32));

            if (!__all(mx <= mrun)) {          // T13: skip rescale
                const float mn = fmaxf(mrun, mx);
                const float scl = __builtin_amdgcn_exp2f((mrun - mn) * C2);
                mrun = mn;
                lrun *= scl;
#pragma unroll
                for (int r = 0; r < 16; ++r) { o0[r] *= scl; o1[r] *= scl; }
            }

            // ---- P = exp2((S - m) * C2), pack to bf16 pairs ----
            float psum = 0.f;
            u32 pk0, pk1, pk2, pk3, pk4, pk5, pk6, pk7;
            {
                float pa, pb;
                pa = __builtin_amdgcn_exp2f((st[0] - mrun) * C2);
                pb = __builtin_amdgcn_exp2f((st[1] - mrun) * C2);
                psum += pa + pb; pk0 = cvtpk(pa, pb);
                pa = __builtin_amdgcn_exp2f((st[2] - mrun) * C2);
                pb = __builtin_amdgcn_exp2f((st[3] - mrun) * C2);
                psum += pa + pb; pk1 = cvtpk(pa, pb);
                pa = __builtin_amdgcn_exp2f((st[4] - mrun) * C2);
                pb = __builtin_amdgcn_exp2f((st[5] - mrun) * C2);
                psum += pa + pb; pk2 = cvtpk(pa, pb);
                pa = __builtin_amdgcn_exp2f((st[6] - mrun) * C2);
                pb = __builtin_amdgcn_exp2f((st[7] - mrun) * C2);
                psum += pa + pb; pk3 = cvtpk(pa, pb);
                pa = __builtin_amdgcn_exp2f((st[8] - mrun) * C2);
                pb = __builtin_amdgcn_exp2f((st[9] - mrun) * C2);
                psum += pa + pb; pk4 = cvtpk(pa, pb);
                pa = __builtin_amdgcn_exp2f((st[10] - mrun) * C2);
                pb = __builtin_amdgcn_exp2f((st[11] - mrun) * C2);
                psum += pa + pb; pk5 = cvtpk(pa, pb);
                pa = __builtin_amdgcn_exp2f((st[12] - mrun) * C2);
                pb = __builtin_amdgcn_exp2f((st[13] - mrun) * C2);
                psum += pa + pb; pk6 = cvtpk(pa, pb);
                pa = __builtin_amdgcn_exp2f((st[14] - mrun) * C2);
                pb = __builtin_amdgcn_exp2f((st[15] - mrun) * C2);
                psum += pa + pb; pk7 = cvtpk(pa, pb);
            }
            lrun += psum;

            // ---- redistribute to PV B-fragments (T12) ----
            plswap(pk0, pk2); plswap(pk1, pk3);
            plswap(pk4, pk6); plswap(pk5, pk7);
            const bf16x8 pf0 = mk8(pk0, pk1, pk2, pk3);   // kv +0..15
            const bf16x8 pf1 = mk8(pk4, pk5, pk6, pk7);   // kv +16..31

            // ---- O^T += V^T P from LDS (A = V^T: row=d, k=kv) ----
#pragma unroll
            for (int dh = 0; dh < 2; ++dh) {
#pragma unroll
                for (int ks = 0; ks < 2; ++ks) {
                    const int row = 32 * dh + lq;
                    const int byte = (64 * s + 32 * ks + 16 * hi) ^ ((row & 7) << 4);
                    const bf16x8 vf = *(const bf16x8*)&Vs[b][(row * 128 + byte) >> 1];
                    if (dh == 0) o0 = mfma32(vf, ks ? pf1 : pf0, o0);
                    else         o1 = mfma32(vf, ks ? pf1 : pf0, o1);
                }
            }
        }
        if (t + 1 < nt) __syncthreads();   // drains this iter's prefetch
    }

    // ---- epilogue: combine partner sums, write Y row (one q per lane) ----
    lrun += __shfl_xor(lrun, 32);
    const float inv = 1.0f / lrun;
    const int bb = bh >> 4, h = bh & 15;
    u16* yrow = Y + (size_t)(bb * TT + qs + lq) * CC + h * DD;
#pragma unroll
    for (int rq = 0; rq < 4; ++rq) {
        const int d0 = 8 * rq + 4 * hi;
        const u32 w0 = cvtpk(o0[rq * 4 + 0] * inv, o0[rq * 4 + 1] * inv);
        const u32 w1 = cvtpk(o0[rq * 4 + 2] * inv, o0[rq * 4 + 3] * inv);
        *(uint2*)&yrow[d0] = make_uint2(w0, w1);
        const u32 w2 = cvtpk(o1[rq * 4 + 0] * inv, o1[rq * 4 + 1] * inv);
        const u32 w3 = cvtpk(o1[rq * 4 + 2] * inv, o1[rq * 4 + 3] * inv);
        *(uint2*)&yrow[32 + d0] = make_uint2(w2, w3);
    }
}

// ---------------------------------------------------------------------------
extern "C" void kernel_launch(void* const* d_in, const int* in_sizes, int n_in,
                              void* d_out, int out_size, void* d_ws, size_t ws_size,
                              hipStream_t stream) {
    const float* X  = (const float*)d_in[0];   // [4,2048,1024] f32
    const float* Wa = (const float*)d_in[1];   // [1024,3072]  f32
    const float* ba = (const float*)d_in[2];   // [3072]       f32
    const float* Wp = (const float*)d_in[3];   // [1024,1024]  f32
    const float* bp = (const float*)d_in[4];   // [1024]       f32
    float* out = (float*)d_out;                // [8192,1024]  f32

    u16* ws  = (u16*)d_ws;
    u16* Xb  = ws;                                    // 8192*1024
    u16* WtA = Xb + (size_t)MROWS * CC;               // 3072*1024
    u16* WtP = WtA + 3072 * 1024;                     // 1024*1024
    u16* Qb  = WtP + 1024 * 1024;                     // 64*2048*64
    u16* Kb  = Qb + (size_t)BHH * TT * DD;
    u16* Vtb = Kb + (size_t)BHH * TT * DD;
    u16* Yb  = Vtb + (size_t)BHH * TT * DD;           // 8192*1024

    k_f2b<<<dim3(MROWS * CC / 1024), 256, 0, stream>>>(X, Xb, MROWS * CC);
    k_transpose_cvt<<<dim3(96, 32), 256, 0, stream>>>(Wa, WtA, 1024, 3072);
    k_transpose_cvt<<<dim3(32, 32), 256, 0, stream>>>(Wp, WtP, 1024, 1024);
    k_gemm_qkv<<<dim3(24, 64), 256, 0, stream>>>(Xb, WtA, ba, Qb, Kb, Vtb);
    k_attn<<<dim3(1024), 256, 0, stream>>>(Qb, Kb, Vtb, Yb);
    k_gemm_proj<<<dim3(8, 64), 256, 0, stream>>>(Yb, WtP, bp, out);
}